// Round 2
// baseline (294.598 us; speedup 1.0000x reference)
//
#include <hip/hip_runtime.h>
#include <math.h>

// Problem constants
#define BH 64      // (b=4) * (h=16) folded leading dim
#define NB 32      // buckets
#define BS 128     // bucket size
#define DHEAD 64   // head dim

typedef __attribute__((ext_vector_type(8))) short bf16x8;
typedef __attribute__((ext_vector_type(4))) float f32x4;

#define LDK 72     // padded row (ushorts) for Kh/Kl [128][72]
#define LDVT 128   // transposed V: Vt[d=64][k=128] ushorts, XOR-swizzled rows
#define LDP 136    // padded row for P [128][136]

// ---------------- threefry2x32 (JAX partitionable PRNG), key = (0, 42) ----------------
__device__ __forceinline__ unsigned rotl32(unsigned x, int d) {
    return (x << d) | (x >> (32 - d));
}

__device__ __forceinline__ void threefry2x32(unsigned k0, unsigned k1,
                                             unsigned& x0, unsigned& x1) {
    const unsigned ks0 = k0, ks1 = k1, ks2 = k0 ^ k1 ^ 0x1BD11BDAu;
    const int r0[4] = {13, 15, 26, 6};
    const int r1[4] = {17, 29, 16, 24};
    x0 += ks0; x1 += ks1;
    #pragma unroll
    for (int i = 0; i < 4; i++) { x0 += x1; x1 = rotl32(x1, r0[i]); x1 ^= x0; }
    x0 += ks1; x1 += ks2 + 1u;
    #pragma unroll
    for (int i = 0; i < 4; i++) { x0 += x1; x1 = rotl32(x1, r1[i]); x1 ^= x0; }
    x0 += ks2; x1 += ks0 + 2u;
    #pragma unroll
    for (int i = 0; i < 4; i++) { x0 += x1; x1 = rotl32(x1, r0[i]); x1 ^= x0; }
    x0 += ks0; x1 += ks1 + 3u;
    #pragma unroll
    for (int i = 0; i < 4; i++) { x0 += x1; x1 = rotl32(x1, r1[i]); x1 ^= x0; }
    x0 += ks1; x1 += ks2 + 4u;
    #pragma unroll
    for (int i = 0; i < 4; i++) { x0 += x1; x1 = rotl32(x1, r0[i]); x1 ^= x0; }
    x0 += ks2; x1 += ks0 + 5u;
}

__device__ __forceinline__ float jax_uniform_part(unsigned f) {
    unsigned x0 = 0u, x1 = f;
    threefry2x32(0u, 42u, x0, x1);
    unsigned bits = x0 ^ x1;
    return __uint_as_float((bits >> 9) | 0x3F800000u) - 1.0f;
}

// ---------------- kernel 1: bucket key sums pl[bh][u][d] ----------------
// 2048 blocks (bh*32+u) x 256 threads: 4 row-groups of 32 rows, LDS reduce.
__global__ void __launch_bounds__(256)
pl_kernel(const float* __restrict__ k, float* __restrict__ pl) {
    int blk = blockIdx.x;             // bh*32 + u
    int g = threadIdx.x >> 6;         // 0..3
    int d = threadIdx.x & 63;
    const float* kp = k + (size_t)blk * 8192 + (size_t)g * 2048 + d;
    float s = 0.f;
    #pragma unroll
    for (int i = 0; i < 32; i++) s += kp[i * 64];
    __shared__ float red[4][64];
    red[g][d] = s;
    __syncthreads();
    if (threadIdx.x < 64)
        pl[blk * 64 + threadIdx.x] = (red[0][threadIdx.x] + red[1][threadIdx.x])
                                   + (red[2][threadIdx.x] + red[3][threadIdx.x]);
}

// ---------------- kernel 2: routing; writes R' = exp(sinkhorn) + I ----------------
__global__ void route_kernel(const float* __restrict__ pl, const float* __restrict__ Wk,
                             float* __restrict__ Rout) {
    int bh = blockIdx.x;            // 64 blocks
    int h = bh & 15;
    int tid = threadIdx.x;          // 1024 threads
    int i = tid >> 5, j = tid & 31; // lanes 0..31 / 32..63 of a wave = rows i, i+1

    __shared__ float plS[NB * DHEAD];
    __shared__ float T[32 * 33];
    __shared__ float colL[32];

    for (int x = tid; x < NB * DHEAD; x += 1024) plS[x] = pl[bh * NB * DHEAD + x];
    __syncthreads();

    float acc = 0.f;
    #pragma unroll 8
    for (int d2 = 0; d2 < DHEAD; d2++)
        acc += plS[i * DHEAD + d2] * Wk[(h * DHEAD + d2) * NB + j];

    unsigned f = (unsigned)bh * 1024u + (unsigned)i * 32u + (unsigned)j;
    float u = jax_uniform_part(f);
    float g = -logf(-logf(u + 1e-6f) + 1e-6f);
    float val = (acc + g) / 0.75f;

    for (int it = 0; it < 5; it++) {
        // row lse over j (32-lane shuffle butterfly)
        float m = val;
        #pragma unroll
        for (int off = 1; off < 32; off <<= 1) m = fmaxf(m, __shfl_xor(m, off, 32));
        float s = expf(val - m);
        #pragma unroll
        for (int off = 1; off < 32; off <<= 1) s += __shfl_xor(s, off, 32);
        val -= m + logf(s);

        // col lse via padded-LDS transpose
        T[i * 33 + j] = val;
        __syncthreads();
        float tv = T[j * 33 + i];       // group i now holds column i over rows j
        float m2 = tv;
        #pragma unroll
        for (int off = 1; off < 32; off <<= 1) m2 = fmaxf(m2, __shfl_xor(m2, off, 32));
        float s2 = expf(tv - m2);
        #pragma unroll
        for (int off = 1; off < 32; off <<= 1) s2 += __shfl_xor(s2, off, 32);
        if (j == 0) colL[i] = m2 + logf(s2);
        __syncthreads();
        val -= colL[j];
    }
    Rout[bh * 1024 + i * 32 + j] = expf(val) + (i == j ? 1.0f : 0.0f);
}

// ---------------- kernel 3: K' = R' * K per bh (R' includes identity) ----------------
__global__ void __launch_bounds__(256)
mix_kernel(const float* __restrict__ k, const float* __restrict__ Rp,
           float* __restrict__ Kp) {
    __shared__ float X[32][260];
    int bh = blockIdx.x >> 5;       // 64 bh x 32 tiles
    int tile = blockIdx.x & 31;
    const size_t kbase = (size_t)bh * 262144;
    const int col0 = tile * 256;

    {   // stage: thread loads 8 float4 from row j = tid>>3
        int j = threadIdx.x >> 3;
        int cs = (threadIdx.x & 7) * 32;
        const float4* src = (const float4*)(k + kbase + (size_t)j * 8192 + col0 + cs);
        #pragma unroll
        for (int t = 0; t < 8; t++)
            *((float4*)&X[j][cs + 4 * t]) = src[t];
    }
    __syncthreads();

    const int col = threadIdx.x;
    float xv[32];
    #pragma unroll
    for (int j = 0; j < 32; j++) xv[j] = X[j][col];

    const float* Rb = Rp + bh * 1024;   // uniform -> s_load
    float* outp = Kp + kbase + col0 + col;
    #pragma unroll 4
    for (int i = 0; i < 32; i++) {
        float acc = 0.f;
        #pragma unroll
        for (int j = 0; j < 32; j++) acc = fmaf(Rb[i * 32 + j], xv[j], acc);
        outp[(size_t)i * 8192] = acc;
    }
}

// ---------------- kernel 4: per-bucket attention via MFMA ----------------
// V staged TRANSPOSED as bf16 Vt[d=64][k=128] (stride LDVT=128 ushorts) so the
// PV B-fragment is ONE aligned ds_read_b128 (was 8x ds_read_u16).  Rows XOR-
// swizzled on the k-offset's 16B-granule bits: swz(c) = ((c^(c>>4))&15)<<3
// (ushort units, bits 3..6 -> within-row, bijective; identical on write+read).
//  - read: quad's 16 lanes have n&15 = l15 -> XOR spans all 16 granules ->
//    64 distinct dwords per quad -> conflict-free.
//  - write: 4 lanes sharing a k row-pair have c differing by 16 -> distinct
//    low bits of c^(c>>4) -> distinct banks -> conflict-free b32 writes.
// LDS 56320 -> 53248 B => 3 blocks/CU (was 2).
__global__ void __launch_bounds__(256)
attn_mfma_kernel(const float* __restrict__ q, const float* __restrict__ Kp,
                 const float* __restrict__ v, float* __restrict__ out) {
    __shared__ __align__(16) unsigned short smem[2 * 128 * LDK + 64 * LDVT];
    unsigned short* KhS = smem;                   // [128][LDK]
    unsigned short* KlS = smem + 128 * LDK;       // [128][LDK]
    unsigned short* VtS = smem + 256 * LDK;       // [64][LDVT], swizzled
    unsigned short* PbS = smem;                   // [128][LDP], aliases Kh+Kl

    const int tid = threadIdx.x;
    const int w = tid >> 6, lane = tid & 63;
    const int quad = lane >> 4, l15 = lane & 15;
    const int row0 = 32 * w;
    const size_t base = (size_t)blockIdx.x * (BS * DHEAD);

    // ---- Q A-fragments (scaled by 1/8 exactly, split hi/lo bf16) ----
    bf16x8 qh[2][2], ql[2][2];
    #pragma unroll
    for (int ti = 0; ti < 2; ti++) {
        #pragma unroll
        for (int kk = 0; kk < 2; kk++) {
            const float* qp = q + base + (size_t)(row0 + 16 * ti + l15) * DHEAD
                              + kk * 32 + quad * 8;
            float4 a = ((const float4*)qp)[0];
            float4 b = ((const float4*)qp)[1];
            float f[8] = {a.x, a.y, a.z, a.w, b.x, b.y, b.z, b.w};
            #pragma unroll
            for (int j = 0; j < 8; j++) {
                float qs = f[j] * 0.125f;                 // exact (pow2)
                unsigned bits = __float_as_uint(qs);
                unsigned short hi = (unsigned short)(bits >> 16);
                float rem = qs - __uint_as_float(bits & 0xFFFF0000u);
                unsigned short lo = (unsigned short)(__float_as_uint(rem) >> 16);
                qh[ti][kk][j] = (short)hi;
                ql[ti][kk][j] = (short)lo;
            }
        }
    }

    // ---- stage K' (split hi/lo, row-major) into LDS ----
    {
        int r = tid >> 1, c0 = (tid & 1) * 32;
        const float* kp = Kp + base + (size_t)r * DHEAD + c0;
        #pragma unroll
        for (int x = 0; x < 8; x++) {
            float4 a = ((const float4*)kp)[x];
            float kf[4] = {a.x, a.y, a.z, a.w};
            #pragma unroll
            for (int y = 0; y < 4; y++) {
                int c = c0 + 4 * x + y;
                unsigned kb = __float_as_uint(kf[y]);
                unsigned short hi = (unsigned short)(kb >> 16);
                float rem = kf[y] - __uint_as_float(kb & 0xFFFF0000u);
                unsigned short lo = (unsigned short)(__float_as_uint(rem) >> 16);
                KhS[r * LDK + c] = hi;
                KlS[r * LDK + c] = lo;
            }
        }
    }

    // ---- stage V transposed (bf16) into LDS: Vt[c][k], row-pair packed b32 ----
    {
        int rp = tid >> 2;              // k row-pair 0..63
        int c0 = (tid & 3) * 16;        // d column group
        const float* v0 = v + base + (size_t)(2 * rp) * DHEAD + c0;
        const float* v1 = v0 + DHEAD;
        #pragma unroll
        for (int x = 0; x < 4; x++) {
            float4 a = ((const float4*)v0)[x];
            float4 b = ((const float4*)v1)[x];
            float fa[4] = {a.x, a.y, a.z, a.w};
            float fb[4] = {b.x, b.y, b.z, b.w};
            #pragma unroll
            for (int y = 0; y < 4; y++) {
                int c = c0 + 4 * x + y;
                unsigned lo = (__float_as_uint(fa[y]) + 0x8000u) >> 16;
                unsigned hi = (__float_as_uint(fb[y]) + 0x8000u) >> 16;
                unsigned swz = ((unsigned)((c ^ (c >> 4)) & 15)) << 3;
                unsigned idx = (unsigned)c * LDVT + (((unsigned)(2 * rp)) ^ swz);
                *(unsigned*)&VtS[idx] = lo | (hi << 16);
            }
        }
    }
    __syncthreads();

    // ---- S = Qs K'^T : 2x8 tiles of 16x16, K=64 (2 chunks), 3 split terms ----
    f32x4 acc[2][8];
    #pragma unroll
    for (int ti = 0; ti < 2; ti++)
        #pragma unroll
        for (int tc = 0; tc < 8; tc++)
            acc[ti][tc] = (f32x4){0.f, 0.f, 0.f, 0.f};

    #pragma unroll
    for (int tc = 0; tc < 8; tc++) {
        const int jrow = 16 * tc + l15;
        bf16x8 bh0 = *(const bf16x8*)&KhS[jrow * LDK + 0  + quad * 8];
        bf16x8 bh1 = *(const bf16x8*)&KhS[jrow * LDK + 32 + quad * 8];
        bf16x8 bl0 = *(const bf16x8*)&KlS[jrow * LDK + 0  + quad * 8];
        bf16x8 bl1 = *(const bf16x8*)&KlS[jrow * LDK + 32 + quad * 8];
        #pragma unroll
        for (int ti = 0; ti < 2; ti++) {
            f32x4 c = acc[ti][tc];
            c = __builtin_amdgcn_mfma_f32_16x16x32_bf16(qh[ti][0], bh0, c, 0, 0, 0);
            c = __builtin_amdgcn_mfma_f32_16x16x32_bf16(qh[ti][1], bh1, c, 0, 0, 0);
            c = __builtin_amdgcn_mfma_f32_16x16x32_bf16(ql[ti][0], bh0, c, 0, 0, 0);
            c = __builtin_amdgcn_mfma_f32_16x16x32_bf16(ql[ti][1], bh1, c, 0, 0, 0);
            c = __builtin_amdgcn_mfma_f32_16x16x32_bf16(qh[ti][0], bl0, c, 0, 0, 0);
            c = __builtin_amdgcn_mfma_f32_16x16x32_bf16(qh[ti][1], bl1, c, 0, 0, 0);
            acc[ti][tc] = c;
        }
    }

    // ---- softmax over full 128 cols ----
    float mrow[2][4], lrow[2][4];
    #pragma unroll
    for (int ti = 0; ti < 2; ti++)
        #pragma unroll
        for (int r = 0; r < 4; r++) {
            float m = acc[ti][0][r];
            #pragma unroll
            for (int tc = 1; tc < 8; tc++) m = fmaxf(m, acc[ti][tc][r]);
            #pragma unroll
            for (int off = 1; off < 16; off <<= 1)
                m = fmaxf(m, __shfl_xor(m, off, 64));
            mrow[ti][r] = m;
        }
    #pragma unroll
    for (int ti = 0; ti < 2; ti++)
        #pragma unroll
        for (int r = 0; r < 4; r++) {
            float s = 0.f;
            #pragma unroll
            for (int tc = 0; tc < 8; tc++) {
                float p = __expf(acc[ti][tc][r] - mrow[ti][r]);
                acc[ti][tc][r] = p;
                s += p;
            }
            #pragma unroll
            for (int off = 1; off < 16; off <<= 1)
                s += __shfl_xor(s, off, 64);
            lrow[ti][r] = s;
        }

    __syncthreads();   // all waves done reading Kh/Kl before P overwrites them

    // ---- write P as bf16 into LDS ----
    #pragma unroll
    for (int ti = 0; ti < 2; ti++)
        #pragma unroll
        for (int tc = 0; tc < 8; tc++)
            #pragma unroll
            for (int r = 0; r < 4; r++) {
                int prow = row0 + 16 * ti + quad * 4 + r;
                unsigned pb = __float_as_uint(acc[ti][tc][r]);
                PbS[prow * LDP + 16 * tc + l15] = (unsigned short)((pb + 0x8000u) >> 16);
            }
    __syncthreads();

    // ---- O = P V : 2x4 tiles, K=128 (4 chunks), V via b128 from transposed LDS ----
    f32x4 oacc[2][4];
    #pragma unroll
    for (int ti = 0; ti < 2; ti++)
        #pragma unroll
        for (int tc = 0; tc < 4; tc++)
            oacc[ti][tc] = (f32x4){0.f, 0.f, 0.f, 0.f};

    #pragma unroll
    for (int kc = 0; kc < 4; kc++) {
        bf16x8 aP[2];
        #pragma unroll
        for (int ti = 0; ti < 2; ti++)
            aP[ti] = *(const bf16x8*)&PbS[(row0 + 16 * ti + l15) * LDP + kc * 32 + quad * 8];
        #pragma unroll
        for (int tc = 0; tc < 4; tc++) {
            unsigned n = (unsigned)(16 * tc + l15);
            unsigned swz = ((n ^ (n >> 4)) & 15u) << 3;
            unsigned idx = n * LDVT + (((unsigned)(kc * 32 + quad * 8)) ^ swz);
            bf16x8 vb = *(const bf16x8*)&VtS[idx];
            #pragma unroll
            for (int ti = 0; ti < 2; ti++)
                oacc[ti][tc] = __builtin_amdgcn_mfma_f32_16x16x32_bf16(aP[ti], vb, oacc[ti][tc], 0, 0, 0);
        }
    }

    // ---- epilogue: normalize and store ----
    float inv[2][4];
    #pragma unroll
    for (int ti = 0; ti < 2; ti++)
        #pragma unroll
        for (int r = 0; r < 4; r++) inv[ti][r] = 1.0f / lrow[ti][r];

    #pragma unroll
    for (int ti = 0; ti < 2; ti++)
        #pragma unroll
        for (int tc = 0; tc < 4; tc++)
            #pragma unroll
            for (int r = 0; r < 4; r++) {
                int orow = row0 + 16 * ti + quad * 4 + r;
                out[base + (size_t)orow * DHEAD + 16 * tc + l15] = oacc[ti][tc][r] * inv[ti][r];
            }
}

extern "C" void kernel_launch(void* const* d_in, const int* in_sizes, int n_in,
                              void* d_out, int out_size, void* d_ws, size_t ws_size,
                              hipStream_t stream) {
    const float* q  = (const float*)d_in[0];
    const float* k  = (const float*)d_in[1];
    const float* v  = (const float*)d_in[2];
    const float* Wk = (const float*)d_in[3];
    float* out = (float*)d_out;

    // ws layout: K' (16777216 f) | pl (131072 f) | R' (65536 f)
    float* Kp = (float*)d_ws;
    float* pl = Kp + (size_t)16777216;
    float* R  = pl + (size_t)131072;

    pl_kernel<<<dim3(BH * NB), dim3(256), 0, stream>>>(k, pl);
    route_kernel<<<dim3(BH), dim3(1024), 0, stream>>>(pl, Wk, R);
    mix_kernel<<<dim3(BH * NB), dim3(256), 0, stream>>>(k, R, Kp);
    attn_mfma_kernel<<<dim3(BH * NB), dim3(256), 0, stream>>>(q, Kp, v, out);
}

// Round 3
// 289.630 us; speedup vs baseline: 1.0172x; 1.0172x over previous
//
#include <hip/hip_runtime.h>
#include <math.h>

// Problem constants
#define BH 64      // (b=4) * (h=16) folded leading dim
#define NB 32      // buckets
#define BS 128     // bucket size
#define DHEAD 64   // head dim

typedef __attribute__((ext_vector_type(8))) short bf16x8;
typedef __attribute__((ext_vector_type(4))) float f32x4;

#define LDVT 128   // transposed V: Vt[d=64][k=128] ushorts, XOR-swizzled rows
#define LDP 136    // padded row for P [128][136]

// K' LDS-image (produced by mix, consumed by attn via global_load_lds):
// per bucket: [plane hi|lo][s=0..127][64 ushorts], granule-swizzled:
//   idx(s,d) = s*64 + (d ^ ((s&7)<<3))     (XOR on bits 3..5 = 16B granule)
// QK b128 read: 16 lanes rows r=0..15, granule g0^(r&7) -> 8 banks x 2 rows
// = 2-way conflict (free). Bucket stride = 16384 ushorts (32 KiB).

// ---------------- threefry2x32 (JAX partitionable PRNG), key = (0, 42) ----------------
__device__ __forceinline__ unsigned rotl32(unsigned x, int d) {
    return (x << d) | (x >> (32 - d));
}

__device__ __forceinline__ void threefry2x32(unsigned k0, unsigned k1,
                                             unsigned& x0, unsigned& x1) {
    const unsigned ks0 = k0, ks1 = k1, ks2 = k0 ^ k1 ^ 0x1BD11BDAu;
    const int r0[4] = {13, 15, 26, 6};
    const int r1[4] = {17, 29, 16, 24};
    x0 += ks0; x1 += ks1;
    #pragma unroll
    for (int i = 0; i < 4; i++) { x0 += x1; x1 = rotl32(x1, r0[i]); x1 ^= x0; }
    x0 += ks1; x1 += ks2 + 1u;
    #pragma unroll
    for (int i = 0; i < 4; i++) { x0 += x1; x1 = rotl32(x1, r1[i]); x1 ^= x0; }
    x0 += ks2; x1 += ks0 + 2u;
    #pragma unroll
    for (int i = 0; i < 4; i++) { x0 += x1; x1 = rotl32(x1, r0[i]); x1 ^= x0; }
    x0 += ks0; x1 += ks1 + 3u;
    #pragma unroll
    for (int i = 0; i < 4; i++) { x0 += x1; x1 = rotl32(x1, r1[i]); x1 ^= x0; }
    x0 += ks1; x1 += ks2 + 4u;
    #pragma unroll
    for (int i = 0; i < 4; i++) { x0 += x1; x1 = rotl32(x1, r0[i]); x1 ^= x0; }
    x0 += ks2; x1 += ks0 + 5u;
}

__device__ __forceinline__ float jax_uniform_part(unsigned f) {
    unsigned x0 = 0u, x1 = f;
    threefry2x32(0u, 42u, x0, x1);
    unsigned bits = x0 ^ x1;
    return __uint_as_float((bits >> 9) | 0x3F800000u) - 1.0f;
}

// ---------------- kernel 1: bucket key sums pl[bh][u][d] ----------------
__global__ void __launch_bounds__(256)
pl_kernel(const float* __restrict__ k, float* __restrict__ pl) {
    int blk = blockIdx.x;             // bh*32 + u
    int g = threadIdx.x >> 6;         // 0..3
    int d = threadIdx.x & 63;
    const float* kp = k + (size_t)blk * 8192 + (size_t)g * 2048 + d;
    float s = 0.f;
    #pragma unroll
    for (int i = 0; i < 32; i++) s += kp[i * 64];
    __shared__ float red[4][64];
    red[g][d] = s;
    __syncthreads();
    if (threadIdx.x < 64)
        pl[blk * 64 + threadIdx.x] = (red[0][threadIdx.x] + red[1][threadIdx.x])
                                   + (red[2][threadIdx.x] + red[3][threadIdx.x]);
}

// ---------------- kernel 2: routing; writes R' = exp(sinkhorn) + I ----------------
__global__ void route_kernel(const float* __restrict__ pl, const float* __restrict__ Wk,
                             float* __restrict__ Rout) {
    int bh = blockIdx.x;            // 64 blocks
    int h = bh & 15;
    int tid = threadIdx.x;          // 1024 threads
    int i = tid >> 5, j = tid & 31;

    __shared__ float plS[NB * DHEAD];
    __shared__ float T[32 * 33];
    __shared__ float colL[32];

    for (int x = tid; x < NB * DHEAD; x += 1024) plS[x] = pl[bh * NB * DHEAD + x];
    __syncthreads();

    float acc = 0.f;
    #pragma unroll 8
    for (int d2 = 0; d2 < DHEAD; d2++)
        acc += plS[i * DHEAD + d2] * Wk[(h * DHEAD + d2) * NB + j];

    unsigned f = (unsigned)bh * 1024u + (unsigned)i * 32u + (unsigned)j;
    float u = jax_uniform_part(f);
    float g = -logf(-logf(u + 1e-6f) + 1e-6f);
    float val = (acc + g) / 0.75f;

    for (int it = 0; it < 5; it++) {
        float m = val;
        #pragma unroll
        for (int off = 1; off < 32; off <<= 1) m = fmaxf(m, __shfl_xor(m, off, 32));
        float s = expf(val - m);
        #pragma unroll
        for (int off = 1; off < 32; off <<= 1) s += __shfl_xor(s, off, 32);
        val -= m + logf(s);

        T[i * 33 + j] = val;
        __syncthreads();
        float tv = T[j * 33 + i];
        float m2 = tv;
        #pragma unroll
        for (int off = 1; off < 32; off <<= 1) m2 = fmaxf(m2, __shfl_xor(m2, off, 32));
        float s2 = expf(tv - m2);
        #pragma unroll
        for (int off = 1; off < 32; off <<= 1) s2 += __shfl_xor(s2, off, 32);
        if (j == 0) colL[i] = m2 + logf(s2);
        __syncthreads();
        val -= colL[j];
    }
    Rout[bh * 1024 + i * 32 + j] = expf(val) + (i == j ? 1.0f : 0.0f);
}

// ---------------- kernel 3: K' = R' * K, output split-bf16 LDS-image ----------------
// Same mixing math as before; converts f32 -> (hi, lo) bf16 split here (mix is
// BW-bound with idle VALU) and stores in the swizzled LDS-image layout so attn
// can stage with async global_load_lds (zero staging VALU there).
__global__ void __launch_bounds__(256)
mix_kernel(const float* __restrict__ k, const float* __restrict__ Rp,
           unsigned short* __restrict__ khl) {
    __shared__ float X[32][260];
    int bh = blockIdx.x >> 5;       // 64 bh x 32 tiles
    int tile = blockIdx.x & 31;
    const size_t kbase = (size_t)bh * 262144;
    const int col0 = tile * 256;

    {   // stage: thread loads 8 float4 from row j = tid>>3
        int j = threadIdx.x >> 3;
        int cs = (threadIdx.x & 7) * 32;
        const float4* src = (const float4*)(k + kbase + (size_t)j * 8192 + col0 + cs);
        #pragma unroll
        for (int t = 0; t < 8; t++)
            *((float4*)&X[j][cs + 4 * t]) = src[t];
    }
    __syncthreads();

    const int col = threadIdx.x;
    float xv[32];
    #pragma unroll
    for (int j = 0; j < 32; j++) xv[j] = X[j][col];

    const float* Rb = Rp + bh * 1024;   // uniform -> s_load
    const int slot = col0 + col;        // flat index into bucket's [128][64]
    const int s = slot >> 6, d = slot & 63;
    const int idx = s * 64 + (d ^ ((s & 7) << 3));   // swizzled LDS-image index

    #pragma unroll 4
    for (int i = 0; i < 32; i++) {
        float acc = 0.f;
        #pragma unroll
        for (int j = 0; j < 32; j++) acc = fmaf(Rb[i * 32 + j], xv[j], acc);
        unsigned kb = __float_as_uint(acc);
        unsigned short hi = (unsigned short)(kb >> 16);
        float rem = acc - __uint_as_float(kb & 0xFFFF0000u);
        unsigned short lo = (unsigned short)(__float_as_uint(rem) >> 16);
        unsigned short* bp = khl + ((size_t)(bh * 32 + i) << 14);  // bucket base
        bp[idx] = hi;
        bp[idx + 8192] = lo;
    }
}

// ---------------- kernel 4: per-bucket attention via MFMA ----------------
// K' staged via 8x async global_load_lds (16B/lane) from the pre-split,
// pre-swizzled image; V staged transposed+swizzled (R2 layout, verified);
// s_setprio(1) around MFMA clusters (T5).
// LDS: Vt 16384 B | Kh 16384 B | Kl 16384 B; P [128][136] aliases Kh/Kl
// (+1024 ushorts of the tail) -> total 51200 B => 3 blocks/CU.
__global__ void __launch_bounds__(256)
attn_mfma_kernel(const float* __restrict__ q, const unsigned short* __restrict__ khl,
                 const float* __restrict__ v, float* __restrict__ out) {
    __shared__ __align__(16) unsigned short smem[8192 + 17408];   // 51200 B
    unsigned short* VtS = smem;                   // [64][LDVT], swizzled
    unsigned short* KhS = smem + 8192;            // [128][64] swizzled plane
    unsigned short* KlS = smem + 16384;           // [128][64] swizzled plane
    unsigned short* PbS = smem + 8192;            // [128][LDP], aliases Kh+Kl

    const int tid = threadIdx.x;
    const int w = tid >> 6, lane = tid & 63;
    const int quad = lane >> 4, l15 = lane & 15;
    const int row0 = 32 * w;
    const size_t base = (size_t)blockIdx.x * (BS * DHEAD);

    // ---- async stage K' planes: 8 chunks x 4096 B, lane-linear ----
    {
        const char* src = (const char*)(khl + ((size_t)blockIdx.x << 14)) + tid * 16;
        char* dst = (char*)KhS + tid * 16;
        #pragma unroll
        for (int c = 0; c < 8; c++)
            __builtin_amdgcn_global_load_lds(
                (const __attribute__((address_space(1))) unsigned int*)(src + c * 4096),
                (__attribute__((address_space(3))) unsigned int*)(dst + c * 4096),
                16, 0, 0);
    }

    // ---- stage V transposed (bf16) into LDS (overlaps async K copies) ----
    {
        int rp = tid >> 2;              // k row-pair 0..63
        int c0 = (tid & 3) * 16;        // d column group
        const float* v0 = v + base + (size_t)(2 * rp) * DHEAD + c0;
        const float* v1 = v0 + DHEAD;
        #pragma unroll
        for (int x = 0; x < 4; x++) {
            float4 a = ((const float4*)v0)[x];
            float4 b = ((const float4*)v1)[x];
            float fa[4] = {a.x, a.y, a.z, a.w};
            float fb[4] = {b.x, b.y, b.z, b.w};
            #pragma unroll
            for (int y = 0; y < 4; y++) {
                int c = c0 + 4 * x + y;
                unsigned lo = (__float_as_uint(fa[y]) + 0x8000u) >> 16;
                unsigned hi = (__float_as_uint(fb[y]) + 0x8000u) >> 16;
                unsigned swz = ((unsigned)((c ^ (c >> 4)) & 15)) << 3;
                unsigned idx = (unsigned)c * LDVT + (((unsigned)(2 * rp)) ^ swz);
                *(unsigned*)&VtS[idx] = lo | (hi << 16);
            }
        }
    }

    // ---- Q A-fragments (scaled by 1/8 exactly, split hi/lo bf16) ----
    bf16x8 qh[2][2], ql[2][2];
    #pragma unroll
    for (int ti = 0; ti < 2; ti++) {
        #pragma unroll
        for (int kk = 0; kk < 2; kk++) {
            const float* qp = q + base + (size_t)(row0 + 16 * ti + l15) * DHEAD
                              + kk * 32 + quad * 8;
            float4 a = ((const float4*)qp)[0];
            float4 b = ((const float4*)qp)[1];
            float f[8] = {a.x, a.y, a.z, a.w, b.x, b.y, b.z, b.w};
            #pragma unroll
            for (int j = 0; j < 8; j++) {
                float qs = f[j] * 0.125f;                 // exact (pow2)
                unsigned bits = __float_as_uint(qs);
                unsigned short hi = (unsigned short)(bits >> 16);
                float rem = qs - __uint_as_float(bits & 0xFFFF0000u);
                unsigned short lo = (unsigned short)(__float_as_uint(rem) >> 16);
                qh[ti][kk][j] = (short)hi;
                ql[ti][kk][j] = (short)lo;
            }
        }
    }
    __syncthreads();   // drains vmcnt(0): async K copies + V writes visible

    // ---- S = Qs K'^T : 2x8 tiles of 16x16, K=64 (2 chunks), 3 split terms ----
    f32x4 acc[2][8];
    #pragma unroll
    for (int ti = 0; ti < 2; ti++)
        #pragma unroll
        for (int tc = 0; tc < 8; tc++)
            acc[ti][tc] = (f32x4){0.f, 0.f, 0.f, 0.f};

    #pragma unroll
    for (int tc = 0; tc < 8; tc++) {
        const int jrow = 16 * tc + l15;
        const int swzk = (jrow & 7) << 3;
        const int rbase = jrow * 64;
        bf16x8 bh0 = *(const bf16x8*)&KhS[rbase + ((quad * 8 + 0)  ^ swzk)];
        bf16x8 bh1 = *(const bf16x8*)&KhS[rbase + ((quad * 8 + 32) ^ swzk)];
        bf16x8 bl0 = *(const bf16x8*)&KlS[rbase + ((quad * 8 + 0)  ^ swzk)];
        bf16x8 bl1 = *(const bf16x8*)&KlS[rbase + ((quad * 8 + 32) ^ swzk)];
        __builtin_amdgcn_s_setprio(1);
        #pragma unroll
        for (int ti = 0; ti < 2; ti++) {
            f32x4 c = acc[ti][tc];
            c = __builtin_amdgcn_mfma_f32_16x16x32_bf16(qh[ti][0], bh0, c, 0, 0, 0);
            c = __builtin_amdgcn_mfma_f32_16x16x32_bf16(qh[ti][1], bh1, c, 0, 0, 0);
            c = __builtin_amdgcn_mfma_f32_16x16x32_bf16(ql[ti][0], bh0, c, 0, 0, 0);
            c = __builtin_amdgcn_mfma_f32_16x16x32_bf16(ql[ti][1], bh1, c, 0, 0, 0);
            c = __builtin_amdgcn_mfma_f32_16x16x32_bf16(qh[ti][0], bl0, c, 0, 0, 0);
            c = __builtin_amdgcn_mfma_f32_16x16x32_bf16(qh[ti][1], bl1, c, 0, 0, 0);
            acc[ti][tc] = c;
        }
        __builtin_amdgcn_s_setprio(0);
    }

    // ---- softmax over full 128 cols ----
    float mrow[2][4], lrow[2][4];
    #pragma unroll
    for (int ti = 0; ti < 2; ti++)
        #pragma unroll
        for (int r = 0; r < 4; r++) {
            float m = acc[ti][0][r];
            #pragma unroll
            for (int tc = 1; tc < 8; tc++) m = fmaxf(m, acc[ti][tc][r]);
            #pragma unroll
            for (int off = 1; off < 16; off <<= 1)
                m = fmaxf(m, __shfl_xor(m, off, 64));
            mrow[ti][r] = m;
        }
    #pragma unroll
    for (int ti = 0; ti < 2; ti++)
        #pragma unroll
        for (int r = 0; r < 4; r++) {
            float s = 0.f;
            #pragma unroll
            for (int tc = 0; tc < 8; tc++) {
                float p = __expf(acc[ti][tc][r] - mrow[ti][r]);
                acc[ti][tc][r] = p;
                s += p;
            }
            #pragma unroll
            for (int off = 1; off < 16; off <<= 1)
                s += __shfl_xor(s, off, 64);
            lrow[ti][r] = s;
        }

    __syncthreads();   // all waves done reading Kh/Kl before P overwrites them

    // ---- write P as bf16 into LDS ----
    #pragma unroll
    for (int ti = 0; ti < 2; ti++)
        #pragma unroll
        for (int tc = 0; tc < 8; tc++)
            #pragma unroll
            for (int r = 0; r < 4; r++) {
                int prow = row0 + 16 * ti + quad * 4 + r;
                unsigned pb = __float_as_uint(acc[ti][tc][r]);
                PbS[prow * LDP + 16 * tc + l15] = (unsigned short)((pb + 0x8000u) >> 16);
            }
    __syncthreads();

    // ---- O = P V : 2x4 tiles, K=128 (4 chunks), V via b128 from transposed LDS ----
    f32x4 oacc[2][4];
    #pragma unroll
    for (int ti = 0; ti < 2; ti++)
        #pragma unroll
        for (int tc = 0; tc < 4; tc++)
            oacc[ti][tc] = (f32x4){0.f, 0.f, 0.f, 0.f};

    #pragma unroll
    for (int kc = 0; kc < 4; kc++) {
        bf16x8 aP[2];
        #pragma unroll
        for (int ti = 0; ti < 2; ti++)
            aP[ti] = *(const bf16x8*)&PbS[(row0 + 16 * ti + l15) * LDP + kc * 32 + quad * 8];
        __builtin_amdgcn_s_setprio(1);
        #pragma unroll
        for (int tc = 0; tc < 4; tc++) {
            unsigned n = (unsigned)(16 * tc + l15);
            unsigned swz = ((n ^ (n >> 4)) & 15u) << 3;
            unsigned idx = n * LDVT + (((unsigned)(kc * 32 + quad * 8)) ^ swz);
            bf16x8 vb = *(const bf16x8*)&VtS[idx];
            #pragma unroll
            for (int ti = 0; ti < 2; ti++)
                oacc[ti][tc] = __builtin_amdgcn_mfma_f32_16x16x32_bf16(aP[ti], vb, oacc[ti][tc], 0, 0, 0);
        }
        __builtin_amdgcn_s_setprio(0);
    }

    // ---- epilogue: normalize and store ----
    float inv[2][4];
    #pragma unroll
    for (int ti = 0; ti < 2; ti++)
        #pragma unroll
        for (int r = 0; r < 4; r++) inv[ti][r] = 1.0f / lrow[ti][r];

    #pragma unroll
    for (int ti = 0; ti < 2; ti++)
        #pragma unroll
        for (int tc = 0; tc < 4; tc++)
            #pragma unroll
            for (int r = 0; r < 4; r++) {
                int orow = row0 + 16 * ti + quad * 4 + r;
                out[base + (size_t)orow * DHEAD + 16 * tc + l15] = oacc[ti][tc][r] * inv[ti][r];
            }
}

extern "C" void kernel_launch(void* const* d_in, const int* in_sizes, int n_in,
                              void* d_out, int out_size, void* d_ws, size_t ws_size,
                              hipStream_t stream) {
    const float* q  = (const float*)d_in[0];
    const float* k  = (const float*)d_in[1];
    const float* v  = (const float*)d_in[2];
    const float* Wk = (const float*)d_in[3];
    float* out = (float*)d_out;

    // ws layout: khl split-bf16 K' image (2048 buckets x 16384 ushorts = 64 MiB)
    //            | pl (131072 f) | R' (65536 f)   -- total 67,895,296 B (same as before)
    unsigned short* khl = (unsigned short*)d_ws;
    float* pl = (float*)(khl + (size_t)33554432);
    float* R  = pl + (size_t)131072;

    pl_kernel<<<dim3(BH * NB), dim3(256), 0, stream>>>(k, pl);
    route_kernel<<<dim3(BH), dim3(1024), 0, stream>>>(pl, Wk, R);
    mix_kernel<<<dim3(BH * NB), dim3(256), 0, stream>>>(k, R, khl);
    attn_mfma_kernel<<<dim3(BH * NB), dim3(256), 0, stream>>>(q, khl, v, out);
}

// Round 4
// 276.267 us; speedup vs baseline: 1.0664x; 1.0484x over previous
//
#include <hip/hip_runtime.h>
#include <math.h>

// Problem constants
#define BH 64      // (b=4) * (h=16) folded leading dim
#define NB 32      // buckets
#define BS 128     // bucket size
#define DHEAD 64   // head dim

typedef __attribute__((ext_vector_type(8))) short bf16x8;
typedef __attribute__((ext_vector_type(4))) float f32x4;

#define LDVT 128   // transposed V: Vt[d=64][k=128] ushorts, XOR-swizzled rows
#define LDP 136    // padded row for P [128][136]

// K' LDS-image (produced by mix, consumed by attn via global_load_lds):
// per bucket: [plane hi|lo][s=0..127][64 ushorts], granule-swizzled:
//   idx(s,d) = s*64 + (d ^ ((s&7)<<3))     (XOR on bits 3..5 = 16B granule)

// ---------------- threefry2x32 (JAX partitionable PRNG), key = (0, 42) ----------------
__device__ __forceinline__ unsigned rotl32(unsigned x, int d) {
    return (x << d) | (x >> (32 - d));
}

__device__ __forceinline__ void threefry2x32(unsigned k0, unsigned k1,
                                             unsigned& x0, unsigned& x1) {
    const unsigned ks0 = k0, ks1 = k1, ks2 = k0 ^ k1 ^ 0x1BD11BDAu;
    const int r0[4] = {13, 15, 26, 6};
    const int r1[4] = {17, 29, 16, 24};
    x0 += ks0; x1 += ks1;
    #pragma unroll
    for (int i = 0; i < 4; i++) { x0 += x1; x1 = rotl32(x1, r0[i]); x1 ^= x0; }
    x0 += ks1; x1 += ks2 + 1u;
    #pragma unroll
    for (int i = 0; i < 4; i++) { x0 += x1; x1 = rotl32(x1, r1[i]); x1 ^= x0; }
    x0 += ks2; x1 += ks0 + 2u;
    #pragma unroll
    for (int i = 0; i < 4; i++) { x0 += x1; x1 = rotl32(x1, r0[i]); x1 ^= x0; }
    x0 += ks0; x1 += ks1 + 3u;
    #pragma unroll
    for (int i = 0; i < 4; i++) { x0 += x1; x1 = rotl32(x1, r1[i]); x1 ^= x0; }
    x0 += ks1; x1 += ks2 + 4u;
    #pragma unroll
    for (int i = 0; i < 4; i++) { x0 += x1; x1 = rotl32(x1, r0[i]); x1 ^= x0; }
    x0 += ks2; x1 += ks0 + 5u;
}

__device__ __forceinline__ float jax_uniform_part(unsigned f) {
    unsigned x0 = 0u, x1 = f;
    threefry2x32(0u, 42u, x0, x1);
    unsigned bits = x0 ^ x1;
    return __uint_as_float((bits >> 9) | 0x3F800000u) - 1.0f;
}

// ---------------- kernel 1: bucket key sums pl[bh][u][d] ----------------
// Vectorized: lane l loads float4 at row (+l/16), col 4*(l&15) -> a wave's 64
// lanes cover 4 full rows = 1024 contiguous bytes per load instr.  Each wave
// handles 32 rows (8 iters x 4 rows); shfl-reduce over row-class, LDS-reduce
// over the 4 waves.
__global__ void __launch_bounds__(256)
pl_kernel(const float* __restrict__ k, float* __restrict__ pl) {
    int blk = blockIdx.x;             // bh*32 + u
    int tid = threadIdx.x;
    int w = tid >> 6, l = tid & 63;
    int rcls = l >> 4, c4 = l & 15;
    const float4* base = (const float4*)(k + (size_t)blk * 8192);

    float4 acc = {0.f, 0.f, 0.f, 0.f};
    #pragma unroll
    for (int t = 0; t < 8; t++) {
        float4 x = base[(w * 32 + t * 4 + rcls) * 16 + c4];
        acc.x += x.x; acc.y += x.y; acc.z += x.z; acc.w += x.w;
    }
    // reduce across row-class (lane bits 4,5)
    #pragma unroll
    for (int off = 16; off < 64; off <<= 1) {
        acc.x += __shfl_xor(acc.x, off);
        acc.y += __shfl_xor(acc.y, off);
        acc.z += __shfl_xor(acc.z, off);
        acc.w += __shfl_xor(acc.w, off);
    }
    __shared__ float4 red[4][16];
    if (rcls == 0) red[w][c4] = acc;
    __syncthreads();
    if (tid < 64) {
        int g = tid >> 2, j = tid & 3;
        float s = ((const float*)&red[0][g])[j] + ((const float*)&red[1][g])[j]
                + ((const float*)&red[2][g])[j] + ((const float*)&red[3][g])[j];
        pl[blk * 64 + tid] = s;
    }
}

// ---------------- kernel 2: routing; writes R' = exp(sinkhorn) + I ----------------
// __expf/__logf: rel err ~1e-6 -> R perturbed ~1e-5, far under the 0.085
// absmax threshold (current margin 5.4x).  Only 64 blocks -> latency-bound on
// the transcendental chain, so the fast ops are the lever.
__global__ void route_kernel(const float* __restrict__ pl, const float* __restrict__ Wk,
                             float* __restrict__ Rout) {
    int bh = blockIdx.x;            // 64 blocks
    int h = bh & 15;
    int tid = threadIdx.x;          // 1024 threads
    int i = tid >> 5, j = tid & 31;

    __shared__ float plS[NB * DHEAD];
    __shared__ float T[32 * 33];
    __shared__ float colL[32];

    for (int x = tid; x < NB * DHEAD; x += 1024) plS[x] = pl[bh * NB * DHEAD + x];
    __syncthreads();

    float acc = 0.f;
    #pragma unroll 8
    for (int d2 = 0; d2 < DHEAD; d2++)
        acc += plS[i * DHEAD + d2] * Wk[(h * DHEAD + d2) * NB + j];

    unsigned f = (unsigned)bh * 1024u + (unsigned)i * 32u + (unsigned)j;
    float u = jax_uniform_part(f);
    float g = -__logf(-__logf(u + 1e-6f) + 1e-6f);
    float val = (acc + g) / 0.75f;

    for (int it = 0; it < 5; it++) {
        float m = val;
        #pragma unroll
        for (int off = 1; off < 32; off <<= 1) m = fmaxf(m, __shfl_xor(m, off, 32));
        float s = __expf(val - m);
        #pragma unroll
        for (int off = 1; off < 32; off <<= 1) s += __shfl_xor(s, off, 32);
        val -= m + __logf(s);

        T[i * 33 + j] = val;
        __syncthreads();
        float tv = T[j * 33 + i];
        float m2 = tv;
        #pragma unroll
        for (int off = 1; off < 32; off <<= 1) m2 = fmaxf(m2, __shfl_xor(m2, off, 32));
        float s2 = __expf(tv - m2);
        #pragma unroll
        for (int off = 1; off < 32; off <<= 1) s2 += __shfl_xor(s2, off, 32);
        if (j == 0) colL[i] = m2 + __logf(s2);
        __syncthreads();
        val -= colL[j];
    }
    Rout[bh * 1024 + i * 32 + j] = __expf(val) + (i == j ? 1.0f : 0.0f);
}

// ---------------- kernel 3: K' = R' * K, output split-bf16 LDS-image ----------------
// Stores now u32 (neighbor-lane pair packed via shfl_xor(1)): col parity ==
// lane parity, and the granule swizzle only touches bits 3..5, so (d, d+1)
// stay adjacent and 4B-aligned after swizzle.  Halves store instructions.
__global__ void __launch_bounds__(256)
mix_kernel(const float* __restrict__ k, const float* __restrict__ Rp,
           unsigned short* __restrict__ khl) {
    __shared__ float X[32][260];
    int bh = blockIdx.x >> 5;       // 64 bh x 32 tiles
    int tile = blockIdx.x & 31;
    const size_t kbase = (size_t)bh * 262144;
    const int col0 = tile * 256;

    {   // stage: thread loads 8 float4 from row j = tid>>3
        int j = threadIdx.x >> 3;
        int cs = (threadIdx.x & 7) * 32;
        const float4* src = (const float4*)(k + kbase + (size_t)j * 8192 + col0 + cs);
        #pragma unroll
        for (int t = 0; t < 8; t++)
            *((float4*)&X[j][cs + 4 * t]) = src[t];
    }
    __syncthreads();

    const int col = threadIdx.x;
    float xv[32];
    #pragma unroll
    for (int j = 0; j < 32; j++) xv[j] = X[j][col];

    const float* Rb = Rp + bh * 1024;   // uniform -> s_load
    const int slot = col0 + col;        // flat index into bucket's [128][64]
    const int s = slot >> 6, d = slot & 63;
    const int idx = s * 64 + (d ^ ((s & 7) << 3));   // swizzled LDS-image index
    const bool even = (col & 1) == 0;

    #pragma unroll 4
    for (int i = 0; i < 32; i++) {
        float acc = 0.f;
        #pragma unroll
        for (int j = 0; j < 32; j++) acc = fmaf(Rb[i * 32 + j], xv[j], acc);
        unsigned kb = __float_as_uint(acc);
        unsigned hiu = kb >> 16;
        float rem = acc - __uint_as_float(kb & 0xFFFF0000u);
        unsigned lou = __float_as_uint(rem) >> 16;
        unsigned oh = (unsigned)__shfl_xor((int)hiu, 1);
        unsigned ol = (unsigned)__shfl_xor((int)lou, 1);
        if (even) {
            unsigned short* bp = khl + ((size_t)(bh * 32 + i) << 14);  // bucket base
            *(unsigned*)&bp[idx]        = hiu | (oh << 16);
            *(unsigned*)&bp[idx + 8192] = lou | (ol << 16);
        }
    }
}

// ---------------- kernel 4: per-bucket attention via MFMA (unchanged from R3) ----------------
__global__ void __launch_bounds__(256)
attn_mfma_kernel(const float* __restrict__ q, const unsigned short* __restrict__ khl,
                 const float* __restrict__ v, float* __restrict__ out) {
    __shared__ __align__(16) unsigned short smem[8192 + 17408];   // 51200 B
    unsigned short* VtS = smem;                   // [64][LDVT], swizzled
    unsigned short* KhS = smem + 8192;            // [128][64] swizzled plane
    unsigned short* KlS = smem + 16384;           // [128][64] swizzled plane
    unsigned short* PbS = smem + 8192;            // [128][LDP], aliases Kh+Kl

    const int tid = threadIdx.x;
    const int w = tid >> 6, lane = tid & 63;
    const int quad = lane >> 4, l15 = lane & 15;
    const int row0 = 32 * w;
    const size_t base = (size_t)blockIdx.x * (BS * DHEAD);

    // ---- async stage K' planes: 8 chunks x 4096 B, lane-linear ----
    {
        const char* src = (const char*)(khl + ((size_t)blockIdx.x << 14)) + tid * 16;
        char* dst = (char*)KhS + tid * 16;
        #pragma unroll
        for (int c = 0; c < 8; c++)
            __builtin_amdgcn_global_load_lds(
                (const __attribute__((address_space(1))) unsigned int*)(src + c * 4096),
                (__attribute__((address_space(3))) unsigned int*)(dst + c * 4096),
                16, 0, 0);
    }

    // ---- stage V transposed (bf16) into LDS (overlaps async K copies) ----
    {
        int rp = tid >> 2;              // k row-pair 0..63
        int c0 = (tid & 3) * 16;        // d column group
        const float* v0 = v + base + (size_t)(2 * rp) * DHEAD + c0;
        const float* v1 = v0 + DHEAD;
        #pragma unroll
        for (int x = 0; x < 4; x++) {
            float4 a = ((const float4*)v0)[x];
            float4 b = ((const float4*)v1)[x];
            float fa[4] = {a.x, a.y, a.z, a.w};
            float fb[4] = {b.x, b.y, b.z, b.w};
            #pragma unroll
            for (int y = 0; y < 4; y++) {
                int c = c0 + 4 * x + y;
                unsigned lo = (__float_as_uint(fa[y]) + 0x8000u) >> 16;
                unsigned hi = (__float_as_uint(fb[y]) + 0x8000u) >> 16;
                unsigned swz = ((unsigned)((c ^ (c >> 4)) & 15)) << 3;
                unsigned idx = (unsigned)c * LDVT + (((unsigned)(2 * rp)) ^ swz);
                *(unsigned*)&VtS[idx] = lo | (hi << 16);
            }
        }
    }

    // ---- Q A-fragments (scaled by 1/8 exactly, split hi/lo bf16) ----
    bf16x8 qh[2][2], ql[2][2];
    #pragma unroll
    for (int ti = 0; ti < 2; ti++) {
        #pragma unroll
        for (int kk = 0; kk < 2; kk++) {
            const float* qp = q + base + (size_t)(row0 + 16 * ti + l15) * DHEAD
                              + kk * 32 + quad * 8;
            float4 a = ((const float4*)qp)[0];
            float4 b = ((const float4*)qp)[1];
            float f[8] = {a.x, a.y, a.z, a.w, b.x, b.y, b.z, b.w};
            #pragma unroll
            for (int j = 0; j < 8; j++) {
                float qs = f[j] * 0.125f;                 // exact (pow2)
                unsigned bits = __float_as_uint(qs);
                unsigned short hi = (unsigned short)(bits >> 16);
                float rem = qs - __uint_as_float(bits & 0xFFFF0000u);
                unsigned short lo = (unsigned short)(__float_as_uint(rem) >> 16);
                qh[ti][kk][j] = (short)hi;
                ql[ti][kk][j] = (short)lo;
            }
        }
    }
    __syncthreads();   // drains vmcnt(0): async K copies + V writes visible

    // ---- S = Qs K'^T : 2x8 tiles of 16x16, K=64 (2 chunks), 3 split terms ----
    f32x4 acc[2][8];
    #pragma unroll
    for (int ti = 0; ti < 2; ti++)
        #pragma unroll
        for (int tc = 0; tc < 8; tc++)
            acc[ti][tc] = (f32x4){0.f, 0.f, 0.f, 0.f};

    #pragma unroll
    for (int tc = 0; tc < 8; tc++) {
        const int jrow = 16 * tc + l15;
        const int swzk = (jrow & 7) << 3;
        const int rbase = jrow * 64;
        bf16x8 bh0 = *(const bf16x8*)&KhS[rbase + ((quad * 8 + 0)  ^ swzk)];
        bf16x8 bh1 = *(const bf16x8*)&KhS[rbase + ((quad * 8 + 32) ^ swzk)];
        bf16x8 bl0 = *(const bf16x8*)&KlS[rbase + ((quad * 8 + 0)  ^ swzk)];
        bf16x8 bl1 = *(const bf16x8*)&KlS[rbase + ((quad * 8 + 32) ^ swzk)];
        __builtin_amdgcn_s_setprio(1);
        #pragma unroll
        for (int ti = 0; ti < 2; ti++) {
            f32x4 c = acc[ti][tc];
            c = __builtin_amdgcn_mfma_f32_16x16x32_bf16(qh[ti][0], bh0, c, 0, 0, 0);
            c = __builtin_amdgcn_mfma_f32_16x16x32_bf16(qh[ti][1], bh1, c, 0, 0, 0);
            c = __builtin_amdgcn_mfma_f32_16x16x32_bf16(ql[ti][0], bh0, c, 0, 0, 0);
            c = __builtin_amdgcn_mfma_f32_16x16x32_bf16(ql[ti][1], bh1, c, 0, 0, 0);
            c = __builtin_amdgcn_mfma_f32_16x16x32_bf16(qh[ti][0], bl0, c, 0, 0, 0);
            c = __builtin_amdgcn_mfma_f32_16x16x32_bf16(qh[ti][1], bl1, c, 0, 0, 0);
            acc[ti][tc] = c;
        }
        __builtin_amdgcn_s_setprio(0);
    }

    // ---- softmax over full 128 cols ----
    float mrow[2][4], lrow[2][4];
    #pragma unroll
    for (int ti = 0; ti < 2; ti++)
        #pragma unroll
        for (int r = 0; r < 4; r++) {
            float m = acc[ti][0][r];
            #pragma unroll
            for (int tc = 1; tc < 8; tc++) m = fmaxf(m, acc[ti][tc][r]);
            #pragma unroll
            for (int off = 1; off < 16; off <<= 1)
                m = fmaxf(m, __shfl_xor(m, off, 64));
            mrow[ti][r] = m;
        }
    #pragma unroll
    for (int ti = 0; ti < 2; ti++)
        #pragma unroll
        for (int r = 0; r < 4; r++) {
            float s = 0.f;
            #pragma unroll
            for (int tc = 0; tc < 8; tc++) {
                float p = __expf(acc[ti][tc][r] - mrow[ti][r]);
                acc[ti][tc][r] = p;
                s += p;
            }
            #pragma unroll
            for (int off = 1; off < 16; off <<= 1)
                s += __shfl_xor(s, off, 64);
            lrow[ti][r] = s;
        }

    __syncthreads();   // all waves done reading Kh/Kl before P overwrites them

    // ---- write P as bf16 into LDS ----
    #pragma unroll
    for (int ti = 0; ti < 2; ti++)
        #pragma unroll
        for (int tc = 0; tc < 8; tc++)
            #pragma unroll
            for (int r = 0; r < 4; r++) {
                int prow = row0 + 16 * ti + quad * 4 + r;
                unsigned pb = __float_as_uint(acc[ti][tc][r]);
                PbS[prow * LDP + 16 * tc + l15] = (unsigned short)((pb + 0x8000u) >> 16);
            }
    __syncthreads();

    // ---- O = P V : 2x4 tiles, K=128 (4 chunks), V via b128 from transposed LDS ----
    f32x4 oacc[2][4];
    #pragma unroll
    for (int ti = 0; ti < 2; ti++)
        #pragma unroll
        for (int tc = 0; tc < 4; tc++)
            oacc[ti][tc] = (f32x4){0.f, 0.f, 0.f, 0.f};

    #pragma unroll
    for (int kc = 0; kc < 4; kc++) {
        bf16x8 aP[2];
        #pragma unroll
        for (int ti = 0; ti < 2; ti++)
            aP[ti] = *(const bf16x8*)&PbS[(row0 + 16 * ti + l15) * LDP + kc * 32 + quad * 8];
        __builtin_amdgcn_s_setprio(1);
        #pragma unroll
        for (int tc = 0; tc < 4; tc++) {
            unsigned n = (unsigned)(16 * tc + l15);
            unsigned swz = ((n ^ (n >> 4)) & 15u) << 3;
            unsigned idx = n * LDVT + (((unsigned)(kc * 32 + quad * 8)) ^ swz);
            bf16x8 vb = *(const bf16x8*)&VtS[idx];
            #pragma unroll
            for (int ti = 0; ti < 2; ti++)
                oacc[ti][tc] = __builtin_amdgcn_mfma_f32_16x16x32_bf16(aP[ti], vb, oacc[ti][tc], 0, 0, 0);
        }
        __builtin_amdgcn_s_setprio(0);
    }

    // ---- epilogue: normalize and store ----
    float inv[2][4];
    #pragma unroll
    for (int ti = 0; ti < 2; ti++)
        #pragma unroll
        for (int r = 0; r < 4; r++) inv[ti][r] = 1.0f / lrow[ti][r];

    #pragma unroll
    for (int ti = 0; ti < 2; ti++)
        #pragma unroll
        for (int tc = 0; tc < 4; tc++)
            #pragma unroll
            for (int r = 0; r < 4; r++) {
                int orow = row0 + 16 * ti + quad * 4 + r;
                out[base + (size_t)orow * DHEAD + 16 * tc + l15] = oacc[ti][tc][r] * inv[ti][r];
            }
}

extern "C" void kernel_launch(void* const* d_in, const int* in_sizes, int n_in,
                              void* d_out, int out_size, void* d_ws, size_t ws_size,
                              hipStream_t stream) {
    const float* q  = (const float*)d_in[0];
    const float* k  = (const float*)d_in[1];
    const float* v  = (const float*)d_in[2];
    const float* Wk = (const float*)d_in[3];
    float* out = (float*)d_out;

    // ws layout: khl split-bf16 K' image (2048 buckets x 16384 ushorts = 64 MiB)
    //            | pl (131072 f) | R' (65536 f)
    unsigned short* khl = (unsigned short*)d_ws;
    float* pl = (float*)(khl + (size_t)33554432);
    float* R  = pl + (size_t)131072;

    pl_kernel<<<dim3(BH * NB), dim3(256), 0, stream>>>(k, pl);
    route_kernel<<<dim3(BH), dim3(1024), 0, stream>>>(pl, Wk, R);
    mix_kernel<<<dim3(BH * NB), dim3(256), 0, stream>>>(k, R, khl);
    attn_mfma_kernel<<<dim3(BH * NB), dim3(256), 0, stream>>>(q, khl, v, out);
}